// Round 9
// baseline (295.226 us; speedup 1.0000x reference)
//
#include <hip/hip_runtime.h>
#include <math.h>

// Problem constants (from reference)
#define NH 4
#define HD 64
#define HIDDEN 256
#define BS 32
#define NB 64          // NUM_BLOCKS = MAX_LEN/BS = 2048/32
#define SCALE 0.125f
#define INV_SCALE 8.0f
#define TILE 64        // tokens per cmp_kernel workgroup (lengths are multiples of 256)
#define TPW 16         // tokens per wave in cmp_kernel

__device__ __forceinline__ float fast_sigmoid(float x) {
    return 1.0f / (1.0f + __expf(-x));
}
__device__ __forceinline__ float readlane_f(float v, int lane) {
    return __int_as_float(__builtin_amdgcn_readlane(__float_as_int(v), lane));
}
__device__ __forceinline__ unsigned long long umax64(unsigned long long a, unsigned long long b) {
    return a > b ? a : b;
}
__device__ __forceinline__ unsigned long long umin64(unsigned long long a, unsigned long long b) {
    return a < b ? a : b;
}

// Kernel 1: block means. K in f64 (selection path must be f64-exact vs the np
// reference), V in f32. Paired layouts (4096 elements per (b,h)):
// k_cmp2 (double): [b][h][dd2][m][par]  (dd2=dd/2, par=dd&1)
// v_cmp2 (float) : [b][h][m2][d][par]   (m2=m/2,  par=m&1)
__global__ __launch_bounds__(256) void kcmp_kernel(
    const float* __restrict__ k, const float* __restrict__ v,
    const int* __restrict__ x_offsets,
    double* __restrict__ k_cmp2, float* __restrict__ v_cmp2) {
    int bb  = blockIdx.x;          // b*NB + blk
    int b   = bb >> 6;
    int blk = bb & 63;
    int tid = threadIdx.x;         // column: h = tid>>6, d = tid&63
    int s0   = x_offsets[b];
    int len  = x_offsets[b + 1] - s0;
    int nblk = len >> 5;
    int h = tid >> 6, d = tid & 63;
    if (blockIdx.y == 0) {
        double acc = 0.0;
        if (blk < nblk) {
            const float* kp = k + (size_t)(s0 + blk * BS) * HIDDEN + tid;
            #pragma unroll
            for (int i = 0; i < BS; ++i) acc += (double)kp[i * HIDDEN];
            acc *= (1.0 / BS);
        }
        k_cmp2[((size_t)(b * NH + h) * 32 + (d >> 1)) * 128 + blk * 2 + (d & 1)] = acc;
    } else {
        float acc = 0.f;
        if (blk < nblk) {
            const float* vp = v + (size_t)(s0 + blk * BS) * HIDDEN + tid;
            #pragma unroll
            for (int i = 0; i < BS; ++i) acc += vp[i * HIDDEN];
            acc *= (1.0f / BS);
        }
        v_cmp2[((size_t)(b * NH + h) * 32 + (blk >> 1)) * 128 + d * 2 + (blk & 1)] = acc;
    }
}

// Kernel 2 (NEW): compressed-path scores + top-k + o_cmp GEMM, one WG per
// (64-token tile, head). k_cmp/v_cmp staged in LDS once -> 64x reuse vs R8
// (which re-read 32KB+16KB per wave per token: the L1-fill bottleneck).
// Selection math identical to R8: f64 means, f64 dot in ascending-dd order,
// f64 silu, monotone-u64 key with packed index, triple-sort butterfly.
__global__ __launch_bounds__(256) void cmp_kernel(
    const float* __restrict__ q,
    const int* __restrict__ batch_ids, const int* __restrict__ pos_ids,
    const double* __restrict__ k_cmp2, const float* __restrict__ v_cmp2,
    float* __restrict__ oc_buf, int2* __restrict__ idxbuf, int T) {
    int t0   = blockIdx.x * TILE;      // all TILE tokens share one sequence
    int h    = blockIdx.y;
    int tid  = threadIdx.x;
    int wv   = tid >> 6;               // wave = 16-token sub-tile
    int lane = tid & 63;
    int b    = batch_ids[t0];          // uniform across tile
    int pos0 = pos_ids[t0];            // positions are contiguous within a tile
    int tw   = t0 + wv * TPW;          // first token of this wave
    int posw = pos0 + wv * TPW;

    __shared__ double Ks[4096];        // paired [dd2][m][par] = double2 per (dd2,m)
    __shared__ float  Vs[4096];        // paired [m2][d][par]
    {
        const double* kg = k_cmp2 + (size_t)(b * NH + h) * 4096;
        const float*  vg = v_cmp2 + (size_t)(b * NH + h) * 4096;
        #pragma unroll
        for (int i = 0; i < 16; ++i) Ks[tid + 256 * i] = kg[tid + 256 * i];
        #pragma unroll
        for (int i = 0; i < 16; ++i) Vs[tid + 256 * i] = vg[tid + 256 * i];
    }
    __syncthreads();

    // q tile in registers: qreg[tt] = q[tw+tt][h*64 + lane]
    float qreg[TPW];
    #pragma unroll
    for (int tt = 0; tt < TPW; ++tt)
        qreg[tt] = q[(size_t)(tw + tt) * HIDDEN + h * HD + lane];

    // ---- f64 scores: lane = block m; 16 tokens per wave ----
    double acc[TPW];
    #pragma unroll
    for (int tt = 0; tt < TPW; ++tt) acc[tt] = 0.0;
    const double2* Ks2 = (const double2*)Ks;
    #pragma unroll 8
    for (int dd2 = 0; dd2 < 32; ++dd2) {
        double2 kk = Ks2[dd2 * 64 + lane];
        #pragma unroll
        for (int tt = 0; tt < TPW; ++tt) {
            float qa = readlane_f(qreg[tt], 2 * dd2);
            float qb = readlane_f(qreg[tt], 2 * dd2 + 1);
            acc[tt] += (double)qa * kk.x;
            acc[tt] += (double)qb * kk.y;
        }
    }

    // ---- per token: silu (f64), key, top-3 butterfly, store idx ----
    float pf[TPW];
    int i0s[TPW], i2s[TPW];
    #pragma unroll
    for (int tt = 0; tt < TPW; ++tt) {
        int qblk = (posw + tt) >> 5;
        double r = acc[tt] * 0.125;
        double p64 = 0.0;
        if (lane <= qblk) p64 = r / (1.0 + exp(-r)) * 8.0;   // silu*INV_SCALE
        double selv = (lane == qblk) ? 1.0 : p64;
        pf[tt] = (float)p64;                                 // exactly 0 beyond qblk
        long long sb = __double_as_longlong(selv);
        unsigned long long k0 = (unsigned long long)sb;
        k0 = (sb < 0) ? ~k0 : (k0 | 0x8000000000000000ull);
        k0 = (k0 & ~63ull) | (unsigned long long)(63 - lane);
        unsigned long long a0 = k0, a1 = 0ull, a2 = 0ull;
        #pragma unroll
        for (int off = 32; off; off >>= 1) {
            unsigned long long b0 = __shfl_xor(a0, off, 64);
            unsigned long long b1 = __shfl_xor(a1, off, 64);
            unsigned long long b2 = __shfl_xor(a2, off, 64);
            unsigned long long M00 = umax64(a0, b0), m01 = umin64(a0, b0);
            unsigned long long M11 = umax64(a1, b1);
            unsigned long long M22 = umax64(a2, b2);
            a0 = M00;
            a1 = umax64(m01, M11);
            a2 = umax64(umin64(m01, M11), M22);
        }
        i0s[tt] = 63 - (int)(a0 & 63ull);
        i2s[tt] = 63 - (int)(a2 & 63ull);
    }
    if (lane == 0) {
        #pragma unroll
        for (int tt = 0; tt < TPW; ++tt)
            idxbuf[(size_t)(tw + tt) * NH + h] = make_int2(i0s[tt], i2s[tt]);
    }

    // ---- o_cmp GEMM vs LDS v_cmp: lane = d; pf broadcasts are 0 past qblk ----
    float occ[TPW];
    #pragma unroll
    for (int tt = 0; tt < TPW; ++tt) occ[tt] = 0.f;
    int mmax = (posw + TPW - 1) >> 5;            // qblk of last token in sub-tile
    const float2* Vs2 = (const float2*)Vs;
    for (int m2 = 0; m2 <= (mmax >> 1); ++m2) {
        float2 vv = Vs2[m2 * 64 + lane];
        #pragma unroll
        for (int tt = 0; tt < TPW; ++tt) {
            occ[tt] += readlane_f(pf[tt], 2 * m2) * vv.x;
            occ[tt] += readlane_f(pf[tt], 2 * m2 + 1) * vv.y;
        }
    }
    #pragma unroll
    for (int tt = 0; tt < TPW; ++tt)
        oc_buf[(size_t)(tw + tt) * HIDDEN + h * HD + lane] = occ[tt];
}

// Kernel 3: per-token gather + LayerNorm. One WG (4 waves) per token.
__global__ __launch_bounds__(256, 8) void hstu_main_kernel(
    const float* __restrict__ q, const float* __restrict__ k,
    const float* __restrict__ v, const float* __restrict__ u,
    const float* __restrict__ Wg_cmp,
    const int* __restrict__ x_offsets, const int* __restrict__ batch_ids,
    const int* __restrict__ pos_ids,
    const float* __restrict__ oc_buf, const int2* __restrict__ idxbuf,
    float* __restrict__ out, int T) {
    int t   = blockIdx.x;
    int tid = threadIdx.x;
    int h = __builtin_amdgcn_readfirstlane(tid >> 6);  // wave-uniform -> SGPR
    int d = tid & 63;
    int b    = batch_ids[t];
    int pos  = pos_ids[t];
    int s0   = x_offsets[b];
    int qblk = pos >> 5;

    int2 ix  = idxbuf[(size_t)t * NH + h];             // uniform -> s_load
    int idx0 = ix.x, idx2 = ix.y;

    const float* qrow = q + (size_t)t * HIDDEN + h * HD;
    float qv = qrow[d];

    // g = sigmoid(q[h] . Wg_cmp[h])
    float gsum = qv * Wg_cmp[h * HD + d];
    #pragma unroll
    for (int off = 32; off; off >>= 1) gsum += __shfl_xor(gsum, off, 64);
    float g = fast_sigmoid(gsum);

    float oc = oc_buf[(size_t)t * HIDDEN + tid] * g;

    // ---- o_slc scores, coalesced: lane=(c,r); 4 its x 16 rows ----
    int r = d & 15, c = d >> 4;
    float4 qf[4];
    {
        const float4* q4 = (const float4*)qrow;
        #pragma unroll
        for (int j = 0; j < 4; ++j) qf[j] = q4[c + 4 * j];
    }
    float pl[4];
    #pragma unroll
    for (int it = 0; it < 4; ++it) {
        int blk_l = (it >= 2) ? idx2 : idx0;           // scalar
        int ii    = (it & 1) * 16 + r;
        int pis   = blk_l * BS + ii;
        int tgt   = s0 + pis;
        if (tgt > T - 1) tgt = T - 1;
        const float4* kr = (const float4*)(k + (size_t)tgt * HIDDEN + h * HD) + c;
        float ps = 0.f;
        #pragma unroll
        for (int j = 0; j < 4; ++j) {
            float4 kk = kr[j * 4];
            ps += qf[j].x * kk.x + qf[j].y * kk.y + qf[j].z * kk.z + qf[j].w * kk.w;
        }
        ps += __shfl_xor(ps, 16, 64);
        ps += __shfl_xor(ps, 32, 64);                  // replicated across c
        float scv = ps * SCALE;
        pl[it] = (pis <= pos) ? scv * fast_sigmoid(scv) * (INV_SCALE * 2.0f) : 0.f;
    }

    // ---- o_slc accumulate: 2x32 unrolled, 4-way split accumulators ----
    int bsafe1 = (idx2 > qblk) ? 0 : idx2;             // pl is 0 there anyway
    const float* vr0 = v + (size_t)(s0 + idx0  * BS) * HIDDEN + h * HD + d;
    const float* vr1 = v + (size_t)(s0 + bsafe1 * BS) * HIDDEN + h * HD + d;
    float os0 = 0.f, os1 = 0.f, os2 = 0.f, os3 = 0.f;
    #pragma unroll
    for (int i = 0; i < 16; ++i) {
        os0 += readlane_f(pl[0], i) * vr0[i * HIDDEN];
        os1 += readlane_f(pl[1], i) * vr0[(16 + i) * HIDDEN];
        os2 += readlane_f(pl[2], i) * vr1[i * HIDDEN];
        os3 += readlane_f(pl[3], i) * vr1[(16 + i) * HIDDEN];
    }
    float os = (os0 + os1) + (os2 + os3);

    // ---- dual LayerNorm over 256 dims + gate by u, sum ----
    __shared__ float red[NH][4];
    float sc_ = oc, sc2 = oc * oc, ss_ = os, ss2 = os * os;
    #pragma unroll
    for (int off = 32; off; off >>= 1) {
        sc_ += __shfl_xor(sc_, off, 64);
        sc2 += __shfl_xor(sc2, off, 64);
        ss_ += __shfl_xor(ss_, off, 64);
        ss2 += __shfl_xor(ss2, off, 64);
    }
    if (d == 0) { red[h][0] = sc_; red[h][1] = sc2; red[h][2] = ss_; red[h][3] = ss2; }
    __syncthreads();
    float tc = 0.f, tc2 = 0.f, ts = 0.f, ts2 = 0.f;
    #pragma unroll
    for (int w = 0; w < NH; ++w) {
        tc += red[w][0]; tc2 += red[w][1]; ts += red[w][2]; ts2 += red[w][3];
    }
    float muc  = tc  * (1.0f / HIDDEN);
    float varc = tc2 * (1.0f / HIDDEN) - muc * muc;
    float mus  = ts  * (1.0f / HIDDEN);
    float vars = ts2 * (1.0f / HIDDEN) - mus * mus;
    float uval = u[(size_t)t * HIDDEN + tid];
    float outv = (oc - muc) * rsqrtf(varc + 1e-6f) * uval
               + (os - mus) * rsqrtf(vars + 1e-6f) * uval;
    out[(size_t)t * HIDDEN + tid] = outv;
}

extern "C" void kernel_launch(void* const* d_in, const int* in_sizes, int n_in,
                              void* d_out, int out_size, void* d_ws, size_t ws_size,
                              hipStream_t stream) {
    const float* q      = (const float*)d_in[0];
    const float* k      = (const float*)d_in[1];
    const float* v      = (const float*)d_in[2];
    const float* u      = (const float*)d_in[3];
    const float* Wg_cmp = (const float*)d_in[4];
    // d_in[5] = Wg_slc: dead code in the reference (computed, never used)
    const int* x_offsets = (const int*)d_in[6];
    const int* batch_ids = (const int*)d_in[7];
    const int* pos_ids   = (const int*)d_in[8];

    int T = in_sizes[0] / HIDDEN;   // 11008; all lengths are multiples of 256
    int B = in_sizes[6] - 1;

    // Workspace layout (all 8-byte aligned): ~13.2 MB total
    double* k_cmp2 = (double*)d_ws;                                  // B*NH*4096 doubles
    float*  v_cmp2 = (float*)(k_cmp2 + (size_t)B * NH * 4096);       // B*NH*4096 floats
    float*  oc_buf = v_cmp2 + (size_t)B * NH * 4096;                 // T*256 floats
    int2*   idxbuf = (int2*)(oc_buf + (size_t)T * HIDDEN);           // T*NH int2

    kcmp_kernel<<<dim3(B * NB, 2), 256, 0, stream>>>(k, v, x_offsets, k_cmp2, v_cmp2);
    cmp_kernel<<<dim3(T / TILE, NH), 256, 0, stream>>>(
        q, batch_ids, pos_ids, k_cmp2, v_cmp2, oc_buf, idxbuf, T);
    hstu_main_kernel<<<T, 256, 0, stream>>>(q, k, v, u, Wg_cmp,
                                            x_offsets, batch_ids, pos_ids,
                                            oc_buf, idxbuf, (float*)d_out, T);
}

// Round 10
// 246.563 us; speedup vs baseline: 1.1974x; 1.1974x over previous
//
#include <hip/hip_runtime.h>
#include <math.h>

// Problem constants (from reference)
#define NH 4
#define HD 64
#define HIDDEN 256
#define BS 32
#define NB 64          // NUM_BLOCKS = MAX_LEN/BS = 2048/32
#define SCALE 0.125f
#define INV_SCALE 8.0f

__device__ __forceinline__ float fast_sigmoid(float x) {
    return 1.0f / (1.0f + __expf(-x));
}
__device__ __forceinline__ float readlane_f(float v, int lane) {
    return __int_as_float(__builtin_amdgcn_readlane(__float_as_int(v), lane));
}

// Kernel 1: block means. K in f64 (selection path must be f64-exact vs the np
// reference), V in f32.
// k_cmp  (double): [b][h][m][dd]      -> uniform/SGPR row reads in cmp_kernel
// v_cmp2 (float) : [b][h][m2][d][par] -> float2 reads in o_cmp phase
__global__ __launch_bounds__(256) void kcmp_kernel(
    const float* __restrict__ k, const float* __restrict__ v,
    const int* __restrict__ x_offsets,
    double* __restrict__ k_cmp, float* __restrict__ v_cmp2) {
    int bb  = blockIdx.x;          // b*NB + blk
    int b   = bb >> 6;
    int blk = bb & 63;
    int tid = threadIdx.x;         // column: h = tid>>6, d = tid&63
    int s0   = x_offsets[b];
    int len  = x_offsets[b + 1] - s0;
    int nblk = len >> 5;
    int h = tid >> 6, d = tid & 63;
    if (blockIdx.y == 0) {
        double acc = 0.0;
        if (blk < nblk) {
            const float* kp = k + (size_t)(s0 + blk * BS) * HIDDEN + tid;
            #pragma unroll
            for (int i = 0; i < BS; ++i) acc += (double)kp[i * HIDDEN];
            acc *= (1.0 / BS);
        }
        k_cmp[((size_t)(b * NH + h) * 64 + blk) * 64 + d] = acc;
    } else {
        float acc = 0.f;
        if (blk < nblk) {
            const float* vp = v + (size_t)(s0 + blk * BS) * HIDDEN + tid;
            #pragma unroll
            for (int i = 0; i < BS; ++i) acc += vp[i * HIDDEN];
            acc *= (1.0f / BS);
        }
        v_cmp2[((size_t)(b * NH + h) * 32 + (blk >> 1)) * 128 + d * 2 + (blk & 1)] = acc;
    }
}

// Kernel 2: cmp scores + top-k + o_cmp. WG = (64-token tile, head); 4 waves.
// Dot phase: lane = token, wave wv owns blocks m in [16wv,16wv+16); q held as
// f64 in 128 VGPRs, k via uniform (SGPR) loads -> 1 v_fma_f64 per MAC, zero
// cross-lane ops. Top-3 = per-lane sorted insert; 4 partials merged in LDS.
// Selection math bit-identical to R9 (f64 means, ascending-dd f64 dot, f64
// silu, monotone-u64 key with packed index).
__global__ __launch_bounds__(256, 3) void cmp_kernel(
    const float* __restrict__ q,
    const int* __restrict__ batch_ids, const int* __restrict__ pos_ids,
    const double* __restrict__ k_cmp, const float* __restrict__ v_cmp2,
    float* __restrict__ oc_buf, int2* __restrict__ idxbuf, int T) {
    int t0   = blockIdx.x * 64;        // tile within one sequence (lengths %256==0)
    int h    = blockIdx.y;
    int tid  = threadIdx.x;
    int wv   = __builtin_amdgcn_readfirstlane(tid >> 6);
    int lane = tid & 63;
    int b    = batch_ids[t0];          // uniform
    int pos0 = pos_ids[t0];            // positions contiguous in tile

    __shared__ __align__(16) char smem[49920];
    float* qs = (float*)smem;                       // [dd][65] padded, 16640 B
    float* ps = qs + 64 * 65;                       // [tok][66] padded, 16896 B
    float* vs = ps + 64 * 66;                       // 4096 floats, 16384 B
    unsigned long long* trip = (unsigned long long*)qs;  // reused after sync

    // stage q (transposed, padded) and v_cmp
    const float* qg = q + (size_t)t0 * HIDDEN + h * HD;
    #pragma unroll
    for (int i = 0; i < 16; ++i) {
        int idx = tid + 256 * i;                    // 4096 elements
        int tok = idx >> 6, dd = idx & 63;
        qs[dd * 65 + tok] = qg[(size_t)tok * HIDDEN + dd];
    }
    const float* vg = v_cmp2 + (size_t)(b * NH + h) * 4096;
    #pragma unroll
    for (int i = 0; i < 16; ++i) vs[tid + 256 * i] = vg[tid + 256 * i];
    __syncthreads();

    // per-lane (=token) q row in f64 registers
    double qd[64];
    #pragma unroll
    for (int dd = 0; dd < 64; ++dd) qd[dd] = (double)qs[dd * 65 + lane];
    int myqblk = (pos0 + lane) >> 5;

    // dot + silu + key + top-3 insert, for this wave's 16 blocks
    unsigned long long a0 = 0ull, a1 = 0ull, a2 = 0ull;
    const double* kcb = k_cmp + ((size_t)(b * NH + h) * 64 + wv * 16) * 64;
    #pragma unroll
    for (int mi = 0; mi < 16; ++mi) {
        int m = wv * 16 + mi;
        const double* kr = kcb + mi * 64;           // uniform -> s_load
        double acc = 0.0;
        #pragma unroll
        for (int dd = 0; dd < 64; ++dd) acc += qd[dd] * kr[dd];
        double r = acc * 0.125;
        double p64 = 0.0;
        if (m <= myqblk) p64 = r / (1.0 + exp(-r)) * 8.0;   // silu*INV_SCALE, f64
        double selv = (m == myqblk) ? 1.0 : p64;
        ps[lane * 66 + m] = (float)p64;             // exactly 0 beyond qblk
        long long sb = __double_as_longlong(selv);
        unsigned long long kk = (unsigned long long)sb;
        kk = (sb < 0) ? ~kk : (kk | 0x8000000000000000ull);
        kk = (kk & ~63ull) | (unsigned long long)(63 - m);
        // sorted insert (keys unique; predicated selects)
        if (kk > a0)      { a2 = a1; a1 = a0; a0 = kk; }
        else if (kk > a1) { a2 = a1; a1 = kk; }
        else if (kk > a2) { a2 = kk; }
    }
    __syncthreads();                                // qs reads done -> reuse as trip
    trip[(wv * 64 + lane) * 3 + 0] = a0;
    trip[(wv * 64 + lane) * 3 + 1] = a1;
    trip[(wv * 64 + lane) * 3 + 2] = a2;
    __syncthreads();

    // merge 4 sorted triples (tournament, 3 picks); wave 0 stores idx
    if (wv == 0) {
        unsigned long long kk2[4][3];
        #pragma unroll
        for (int w = 0; w < 4; ++w)
            #pragma unroll
            for (int j = 0; j < 3; ++j)
                kk2[w][j] = trip[(w * 64 + lane) * 3 + j];
        int pp[4] = {0, 0, 0, 0};
        int outi[3];
        #pragma unroll
        for (int s = 0; s < 3; ++s) {
            unsigned long long best = 0ull; int bw = 0;
            #pragma unroll
            for (int w = 0; w < 4; ++w) {
                unsigned long long hd_ = (pp[w] == 0) ? kk2[w][0]
                                       : (pp[w] == 1) ? kk2[w][1] : kk2[w][2];
                if (hd_ > best) { best = hd_; bw = w; }
            }
            outi[s] = 63 - (int)(best & 63ull);
            #pragma unroll
            for (int w = 0; w < 4; ++w) if (w == bw) pp[w]++;
        }
        idxbuf[(size_t)(t0 + lane) * NH + h] = make_int2(outi[0], outi[2]);
    }

    // o_cmp: wave wv -> tokens [16wv,16wv+16), lane = d
    float occ[16];
    #pragma unroll
    for (int tt = 0; tt < 16; ++tt) occ[tt] = 0.f;
    int mmax2 = ((pos0 + 63) >> 5) >> 1;            // pair bound, covers tile
    const float2* vs2 = (const float2*)vs;
    for (int m2 = 0; m2 <= mmax2; ++m2) {
        float2 vv = vs2[m2 * 64 + lane];
        #pragma unroll
        for (int tt = 0; tt < 16; ++tt) {
            int tok = wv * 16 + tt;
            float2 pv = *(const float2*)(ps + tok * 66 + 2 * m2);  // uniform b64
            occ[tt] += pv.x * vv.x + pv.y * vv.y;
        }
    }
    #pragma unroll
    for (int tt = 0; tt < 16; ++tt)
        oc_buf[(size_t)(t0 + wv * 16 + tt) * HIDDEN + h * HD + lane] = occ[tt];
}

// Kernel 3: per-token gather + LayerNorm. One WG (4 waves) per token.
// (unchanged from R9 — measured 123 µs)
__global__ __launch_bounds__(256, 8) void hstu_main_kernel(
    const float* __restrict__ q, const float* __restrict__ k,
    const float* __restrict__ v, const float* __restrict__ u,
    const float* __restrict__ Wg_cmp,
    const int* __restrict__ x_offsets, const int* __restrict__ batch_ids,
    const int* __restrict__ pos_ids,
    const float* __restrict__ oc_buf, const int2* __restrict__ idxbuf,
    float* __restrict__ out, int T) {
    int t   = blockIdx.x;
    int tid = threadIdx.x;
    int h = __builtin_amdgcn_readfirstlane(tid >> 6);
    int d = tid & 63;
    int b    = batch_ids[t];
    int pos  = pos_ids[t];
    int s0   = x_offsets[b];
    int qblk = pos >> 5;

    int2 ix  = idxbuf[(size_t)t * NH + h];
    int idx0 = ix.x, idx2 = ix.y;

    const float* qrow = q + (size_t)t * HIDDEN + h * HD;
    float qv = qrow[d];

    float gsum = qv * Wg_cmp[h * HD + d];
    #pragma unroll
    for (int off = 32; off; off >>= 1) gsum += __shfl_xor(gsum, off, 64);
    float g = fast_sigmoid(gsum);

    float oc = oc_buf[(size_t)t * HIDDEN + tid] * g;

    int r = d & 15, c = d >> 4;
    float4 qf[4];
    {
        const float4* q4 = (const float4*)qrow;
        #pragma unroll
        for (int j = 0; j < 4; ++j) qf[j] = q4[c + 4 * j];
    }
    float pl[4];
    #pragma unroll
    for (int it = 0; it < 4; ++it) {
        int blk_l = (it >= 2) ? idx2 : idx0;
        int ii    = (it & 1) * 16 + r;
        int pis   = blk_l * BS + ii;
        int tgt   = s0 + pis;
        if (tgt > T - 1) tgt = T - 1;
        const float4* kr = (const float4*)(k + (size_t)tgt * HIDDEN + h * HD) + c;
        float psum = 0.f;
        #pragma unroll
        for (int j = 0; j < 4; ++j) {
            float4 kk = kr[j * 4];
            psum += qf[j].x * kk.x + qf[j].y * kk.y + qf[j].z * kk.z + qf[j].w * kk.w;
        }
        psum += __shfl_xor(psum, 16, 64);
        psum += __shfl_xor(psum, 32, 64);
        float scv = psum * SCALE;
        pl[it] = (pis <= pos) ? scv * fast_sigmoid(scv) * (INV_SCALE * 2.0f) : 0.f;
    }

    int bsafe1 = (idx2 > qblk) ? 0 : idx2;
    const float* vr0 = v + (size_t)(s0 + idx0  * BS) * HIDDEN + h * HD + d;
    const float* vr1 = v + (size_t)(s0 + bsafe1 * BS) * HIDDEN + h * HD + d;
    float os0 = 0.f, os1 = 0.f, os2 = 0.f, os3 = 0.f;
    #pragma unroll
    for (int i = 0; i < 16; ++i) {
        os0 += readlane_f(pl[0], i) * vr0[i * HIDDEN];
        os1 += readlane_f(pl[1], i) * vr0[(16 + i) * HIDDEN];
        os2 += readlane_f(pl[2], i) * vr1[i * HIDDEN];
        os3 += readlane_f(pl[3], i) * vr1[(16 + i) * HIDDEN];
    }
    float os = (os0 + os1) + (os2 + os3);

    __shared__ float red[NH][4];
    float sc_ = oc, sc2 = oc * oc, ss_ = os, ss2 = os * os;
    #pragma unroll
    for (int off = 32; off; off >>= 1) {
        sc_ += __shfl_xor(sc_, off, 64);
        sc2 += __shfl_xor(sc2, off, 64);
        ss_ += __shfl_xor(ss_, off, 64);
        ss2 += __shfl_xor(ss2, off, 64);
    }
    if (d == 0) { red[h][0] = sc_; red[h][1] = sc2; red[h][2] = ss_; red[h][3] = ss2; }
    __syncthreads();
    float tc = 0.f, tc2 = 0.f, ts = 0.f, ts2 = 0.f;
    #pragma unroll
    for (int w = 0; w < NH; ++w) {
        tc += red[w][0]; tc2 += red[w][1]; ts += red[w][2]; ts2 += red[w][3];
    }
    float muc  = tc  * (1.0f / HIDDEN);
    float varc = tc2 * (1.0f / HIDDEN) - muc * muc;
    float mus  = ts  * (1.0f / HIDDEN);
    float vars = ts2 * (1.0f / HIDDEN) - mus * mus;
    float uval = u[(size_t)t * HIDDEN + tid];
    float outv = (oc - muc) * rsqrtf(varc + 1e-6f) * uval
               + (os - mus) * rsqrtf(vars + 1e-6f) * uval;
    out[(size_t)t * HIDDEN + tid] = outv;
}

extern "C" void kernel_launch(void* const* d_in, const int* in_sizes, int n_in,
                              void* d_out, int out_size, void* d_ws, size_t ws_size,
                              hipStream_t stream) {
    const float* q      = (const float*)d_in[0];
    const float* k      = (const float*)d_in[1];
    const float* v      = (const float*)d_in[2];
    const float* u      = (const float*)d_in[3];
    const float* Wg_cmp = (const float*)d_in[4];
    // d_in[5] = Wg_slc: dead code in the reference (computed, never used)
    const int* x_offsets = (const int*)d_in[6];
    const int* batch_ids = (const int*)d_in[7];
    const int* pos_ids   = (const int*)d_in[8];

    int T = in_sizes[0] / HIDDEN;   // 11008; all lengths are multiples of 256
    int B = in_sizes[6] - 1;

    double* k_cmp  = (double*)d_ws;                                 // B*NH*4096 doubles
    float*  v_cmp2 = (float*)(k_cmp + (size_t)B * NH * 4096);       // B*NH*4096 floats
    float*  oc_buf = v_cmp2 + (size_t)B * NH * 4096;                // T*256 floats
    int2*   idxbuf = (int2*)(oc_buf + (size_t)T * HIDDEN);          // T*NH int2

    kcmp_kernel<<<dim3(B * NB, 2), 256, 0, stream>>>(k, v, x_offsets, k_cmp, v_cmp2);
    cmp_kernel<<<dim3(T / 64, NH), 256, 0, stream>>>(
        q, batch_ids, pos_ids, k_cmp, v_cmp2, oc_buf, idxbuf, T);
    hstu_main_kernel<<<T, 256, 0, stream>>>(q, k, v, u, Wg_cmp,
                                            x_offsets, batch_ids, pos_ids,
                                            oc_buf, idxbuf, (float*)d_out, T);
}

// Round 11
// 240.864 us; speedup vs baseline: 1.2257x; 1.0237x over previous
//
#include <hip/hip_runtime.h>
#include <math.h>

// Problem constants (from reference)
#define NH 4
#define HD 64
#define HIDDEN 256
#define BS 32
#define NB 64          // NUM_BLOCKS = MAX_LEN/BS = 2048/32
#define SCALE 0.125f
#define INV_SCALE 8.0f

__device__ __forceinline__ float fast_sigmoid(float x) {
    return 1.0f / (1.0f + __expf(-x));
}
__device__ __forceinline__ float readlane_f(float v, int lane) {
    return __int_as_float(__builtin_amdgcn_readlane(__float_as_int(v), lane));
}

// Kernel 1 (unchanged): block means. K in f64 (selection path f64-exact vs np
// reference), V in f32.
// k_cmp  (double): [b][h][m][dd]      -> uniform/SGPR row reads in cmp_kernel
// v_cmp2 (float) : [b][h][m2][d][par] -> float2 reads in o_cmp phase
__global__ __launch_bounds__(256) void kcmp_kernel(
    const float* __restrict__ k, const float* __restrict__ v,
    const int* __restrict__ x_offsets,
    double* __restrict__ k_cmp, float* __restrict__ v_cmp2) {
    int bb  = blockIdx.x;          // b*NB + blk
    int b   = bb >> 6;
    int blk = bb & 63;
    int tid = threadIdx.x;         // column: h = tid>>6, d = tid&63
    int s0   = x_offsets[b];
    int len  = x_offsets[b + 1] - s0;
    int nblk = len >> 5;
    int h = tid >> 6, d = tid & 63;
    if (blockIdx.y == 0) {
        double acc = 0.0;
        if (blk < nblk) {
            const float* kp = k + (size_t)(s0 + blk * BS) * HIDDEN + tid;
            #pragma unroll
            for (int i = 0; i < BS; ++i) acc += (double)kp[i * HIDDEN];
            acc *= (1.0 / BS);
        }
        k_cmp[((size_t)(b * NH + h) * 64 + blk) * 64 + d] = acc;
    } else {
        float acc = 0.f;
        if (blk < nblk) {
            const float* vp = v + (size_t)(s0 + blk * BS) * HIDDEN + tid;
            #pragma unroll
            for (int i = 0; i < BS; ++i) acc += vp[i * HIDDEN];
            acc *= (1.0f / BS);
        }
        v_cmp2[((size_t)(b * NH + h) * 32 + (blk >> 1)) * 128 + d * 2 + (blk & 1)] = acc;
    }
}

// Kernel 2: cmp scores + top-k + o_cmp. WG = (64-token tile, head); 4 waves.
// NEW vs R10: causal wave-skip (wave wv computes its 16 blocks only when
// 16wv <= qblk_max+2 — omitted blocks provably never enter any token's top-3
// because included zero-class candidates qblk_t+1, qblk_t+2 dominate them by
// index order), and the f64 dot uses a 2-way split accumulator for ILP
// (selection flip would require |p-1| < ~1e-15: never).
__global__ __launch_bounds__(256, 3) void cmp_kernel(
    const float* __restrict__ q,
    const int* __restrict__ batch_ids, const int* __restrict__ pos_ids,
    const double* __restrict__ k_cmp, const float* __restrict__ v_cmp2,
    float* __restrict__ oc_buf, int2* __restrict__ idxbuf, int T) {
    int t0   = blockIdx.x * 64;        // tile within one sequence (lengths %256==0)
    int h    = blockIdx.y;
    int tid  = threadIdx.x;
    int wv   = __builtin_amdgcn_readfirstlane(tid >> 6);
    int lane = tid & 63;
    int b    = batch_ids[t0];          // uniform
    int pos0 = pos_ids[t0];            // positions contiguous in tile

    __shared__ __align__(16) char smem[49920];
    float* qs = (float*)smem;                       // [dd][65] padded, 16640 B
    float* ps = qs + 64 * 65;                       // [tok][66] padded, 16896 B
    float* vs = ps + 64 * 66;                       // 4096 floats, 16384 B
    unsigned long long* trip = (unsigned long long*)qs;  // reused after sync

    // stage q (transposed, padded) and v_cmp
    const float* qg = q + (size_t)t0 * HIDDEN + h * HD;
    #pragma unroll
    for (int i = 0; i < 16; ++i) {
        int idx = tid + 256 * i;                    // 4096 elements
        int tok = idx >> 6, dd = idx & 63;
        qs[dd * 65 + tok] = qg[(size_t)tok * HIDDEN + dd];
    }
    const float* vg = v_cmp2 + (size_t)(b * NH + h) * 4096;
    #pragma unroll
    for (int i = 0; i < 16; ++i) vs[tid + 256 * i] = vg[tid + 256 * i];
    __syncthreads();

    int qblk_max = (pos0 + 63) >> 5;
    int m_need   = qblk_max + 2;       // max block index any token's top-3 can touch
    if (m_need > 63) m_need = 63;

    unsigned long long a0 = 0ull, a1 = 0ull, a2 = 0ull;
    if (16 * wv <= m_need) {           // wave-uniform causal skip
        // per-lane (=token) q row in f64 registers
        double qd[64];
        #pragma unroll
        for (int dd = 0; dd < 64; ++dd) qd[dd] = (double)qs[dd * 65 + lane];
        int myqblk = (pos0 + lane) >> 5;

        const double* kcb = k_cmp + ((size_t)(b * NH + h) * 64 + wv * 16) * 64;
        #pragma unroll
        for (int mi = 0; mi < 16; ++mi) {
            int m = wv * 16 + mi;
            const double* kr = kcb + mi * 64;       // uniform -> s_load
            double accA = 0.0, accB = 0.0;          // 2-way split for ILP
            #pragma unroll
            for (int dd = 0; dd < 32; ++dd) {
                accA += qd[2 * dd]     * kr[2 * dd];
                accB += qd[2 * dd + 1] * kr[2 * dd + 1];
            }
            double r = (accA + accB) * 0.125;
            double p64 = 0.0;
            if (m <= myqblk) p64 = r / (1.0 + exp(-r)) * 8.0;   // silu*INV_SCALE
            double selv = (m == myqblk) ? 1.0 : p64;
            ps[lane * 66 + m] = (float)p64;         // exactly 0 beyond qblk
            long long sb = __double_as_longlong(selv);
            unsigned long long kk = (unsigned long long)sb;
            kk = (sb < 0) ? ~kk : (kk | 0x8000000000000000ull);
            kk = (kk & ~63ull) | (unsigned long long)(63 - m);
            // sorted insert (keys unique; predicated selects)
            if (kk > a0)      { a2 = a1; a1 = a0; a0 = kk; }
            else if (kk > a1) { a2 = a1; a1 = kk; }
            else if (kk > a2) { a2 = kk; }
        }
    }
    __syncthreads();                                // qs reads done -> reuse as trip
    trip[(wv * 64 + lane) * 3 + 0] = a0;
    trip[(wv * 64 + lane) * 3 + 1] = a1;
    trip[(wv * 64 + lane) * 3 + 2] = a2;
    __syncthreads();

    // merge 4 sorted triples (tournament, 3 picks); wave 0 stores idx
    if (wv == 0) {
        unsigned long long kk2[4][3];
        #pragma unroll
        for (int w = 0; w < 4; ++w)
            #pragma unroll
            for (int j = 0; j < 3; ++j)
                kk2[w][j] = trip[(w * 64 + lane) * 3 + j];
        int pp[4] = {0, 0, 0, 0};
        int outi[3];
        #pragma unroll
        for (int s = 0; s < 3; ++s) {
            unsigned long long best = 0ull; int bw = 0;
            #pragma unroll
            for (int w = 0; w < 4; ++w) {
                unsigned long long hd_ = (pp[w] == 0) ? kk2[w][0]
                                       : (pp[w] == 1) ? kk2[w][1] : kk2[w][2];
                if (hd_ > best) { best = hd_; bw = w; }
            }
            outi[s] = 63 - (int)(best & 63ull);
            #pragma unroll
            for (int w = 0; w < 4; ++w) if (w == bw) pp[w]++;
        }
        idxbuf[(size_t)(t0 + lane) * NH + h] = make_int2(outi[0], outi[2]);
    }

    // o_cmp: wave wv -> tokens [16wv,16wv+16), lane = d
    float occ[16];
    #pragma unroll
    for (int tt = 0; tt < 16; ++tt) occ[tt] = 0.f;
    int mmax2 = qblk_max >> 1;                      // pair bound, covers tile
    const float2* vs2 = (const float2*)vs;
    for (int m2 = 0; m2 <= mmax2; ++m2) {
        float2 vv = vs2[m2 * 64 + lane];
        #pragma unroll
        for (int tt = 0; tt < 16; ++tt) {
            int tok = wv * 16 + tt;
            float2 pv = *(const float2*)(ps + tok * 66 + 2 * m2);  // uniform b64
            occ[tt] += pv.x * vv.x + pv.y * vv.y;
        }
    }
    #pragma unroll
    for (int tt = 0; tt < 16; ++tt)
        oc_buf[(size_t)(t0 + wv * 16 + tt) * HIDDEN + h * HD + lane] = occ[tt];
}

// Kernel 3: per-token gather + LayerNorm. One WG (4 waves) per token.
// NEW vs R10: XCD-locality swizzle — WG i lands on XCD i&7 (round-robin
// heuristic); give each XCD a contiguous token range so its ~3-6 MB gather
// working set fits the per-XCD 4 MB L2 instead of thrashing through L3.
__global__ __launch_bounds__(256, 8) void hstu_main_kernel(
    const float* __restrict__ q, const float* __restrict__ k,
    const float* __restrict__ v, const float* __restrict__ u,
    const float* __restrict__ Wg_cmp,
    const int* __restrict__ x_offsets, const int* __restrict__ batch_ids,
    const int* __restrict__ pos_ids,
    const float* __restrict__ oc_buf, const int2* __restrict__ idxbuf,
    float* __restrict__ out, int T) {
    int i   = blockIdx.x;
    int t   = ((T & 7) == 0) ? ((i & 7) * (T >> 3) + (i >> 3)) : i;
    int tid = threadIdx.x;
    int h = __builtin_amdgcn_readfirstlane(tid >> 6);
    int d = tid & 63;
    int b    = batch_ids[t];
    int pos  = pos_ids[t];
    int s0   = x_offsets[b];
    int qblk = pos >> 5;

    int2 ix  = idxbuf[(size_t)t * NH + h];
    int idx0 = ix.x, idx2 = ix.y;

    const float* qrow = q + (size_t)t * HIDDEN + h * HD;
    float qv = qrow[d];

    float gsum = qv * Wg_cmp[h * HD + d];
    #pragma unroll
    for (int off = 32; off; off >>= 1) gsum += __shfl_xor(gsum, off, 64);
    float g = fast_sigmoid(gsum);

    float oc = oc_buf[(size_t)t * HIDDEN + tid] * g;

    int r = d & 15, c = d >> 4;
    float4 qf[4];
    {
        const float4* q4 = (const float4*)qrow;
        #pragma unroll
        for (int j = 0; j < 4; ++j) qf[j] = q4[c + 4 * j];
    }
    float pl[4];
    #pragma unroll
    for (int it = 0; it < 4; ++it) {
        int blk_l = (it >= 2) ? idx2 : idx0;
        int ii    = (it & 1) * 16 + r;
        int pis   = blk_l * BS + ii;
        int tgt   = s0 + pis;
        if (tgt > T - 1) tgt = T - 1;
        const float4* kr = (const float4*)(k + (size_t)tgt * HIDDEN + h * HD) + c;
        float psum = 0.f;
        #pragma unroll
        for (int j = 0; j < 4; ++j) {
            float4 kk = kr[j * 4];
            psum += qf[j].x * kk.x + qf[j].y * kk.y + qf[j].z * kk.z + qf[j].w * kk.w;
        }
        psum += __shfl_xor(psum, 16, 64);
        psum += __shfl_xor(psum, 32, 64);
        float scv = psum * SCALE;
        pl[it] = (pis <= pos) ? scv * fast_sigmoid(scv) * (INV_SCALE * 2.0f) : 0.f;
    }

    int bsafe1 = (idx2 > qblk) ? 0 : idx2;
    const float* vr0 = v + (size_t)(s0 + idx0  * BS) * HIDDEN + h * HD + d;
    const float* vr1 = v + (size_t)(s0 + bsafe1 * BS) * HIDDEN + h * HD + d;
    float os0 = 0.f, os1 = 0.f, os2 = 0.f, os3 = 0.f;
    #pragma unroll
    for (int i2 = 0; i2 < 16; ++i2) {
        os0 += readlane_f(pl[0], i2) * vr0[i2 * HIDDEN];
        os1 += readlane_f(pl[1], i2) * vr0[(16 + i2) * HIDDEN];
        os2 += readlane_f(pl[2], i2) * vr1[i2 * HIDDEN];
        os3 += readlane_f(pl[3], i2) * vr1[(16 + i2) * HIDDEN];
    }
    float os = (os0 + os1) + (os2 + os3);

    __shared__ float red[NH][4];
    float sc_ = oc, sc2 = oc * oc, ss_ = os, ss2 = os * os;
    #pragma unroll
    for (int off = 32; off; off >>= 1) {
        sc_ += __shfl_xor(sc_, off, 64);
        sc2 += __shfl_xor(sc2, off, 64);
        ss_ += __shfl_xor(ss_, off, 64);
        ss2 += __shfl_xor(ss2, off, 64);
    }
    if (d == 0) { red[h][0] = sc_; red[h][1] = sc2; red[h][2] = ss_; red[h][3] = ss2; }
    __syncthreads();
    float tc = 0.f, tc2 = 0.f, ts = 0.f, ts2 = 0.f;
    #pragma unroll
    for (int w = 0; w < NH; ++w) {
        tc += red[w][0]; tc2 += red[w][1]; ts += red[w][2]; ts2 += red[w][3];
    }
    float muc  = tc  * (1.0f / HIDDEN);
    float varc = tc2 * (1.0f / HIDDEN) - muc * muc;
    float mus  = ts  * (1.0f / HIDDEN);
    float vars = ts2 * (1.0f / HIDDEN) - mus * mus;
    float uval = u[(size_t)t * HIDDEN + tid];
    float outv = (oc - muc) * rsqrtf(varc + 1e-6f) * uval
               + (os - mus) * rsqrtf(vars + 1e-6f) * uval;
    out[(size_t)t * HIDDEN + tid] = outv;
}

extern "C" void kernel_launch(void* const* d_in, const int* in_sizes, int n_in,
                              void* d_out, int out_size, void* d_ws, size_t ws_size,
                              hipStream_t stream) {
    const float* q      = (const float*)d_in[0];
    const float* k      = (const float*)d_in[1];
    const float* v      = (const float*)d_in[2];
    const float* u      = (const float*)d_in[3];
    const float* Wg_cmp = (const float*)d_in[4];
    // d_in[5] = Wg_slc: dead code in the reference (computed, never used)
    const int* x_offsets = (const int*)d_in[6];
    const int* batch_ids = (const int*)d_in[7];
    const int* pos_ids   = (const int*)d_in[8];

    int T = in_sizes[0] / HIDDEN;   // 11008; all lengths are multiples of 256
    int B = in_sizes[6] - 1;

    double* k_cmp  = (double*)d_ws;                                 // B*NH*4096 doubles
    float*  v_cmp2 = (float*)(k_cmp + (size_t)B * NH * 4096);       // B*NH*4096 floats
    float*  oc_buf = v_cmp2 + (size_t)B * NH * 4096;                // T*256 floats
    int2*   idxbuf = (int2*)(oc_buf + (size_t)T * HIDDEN);          // T*NH int2

    kcmp_kernel<<<dim3(B * NB, 2), 256, 0, stream>>>(k, v, x_offsets, k_cmp, v_cmp2);
    cmp_kernel<<<dim3(T / 64, NH), 256, 0, stream>>>(
        q, batch_ids, pos_ids, k_cmp, v_cmp2, oc_buf, idxbuf, T);
    hstu_main_kernel<<<T, 256, 0, stream>>>(q, k, v, u, Wg_cmp,
                                            x_offsets, batch_ids, pos_ids,
                                            oc_buf, idxbuf, (float*)d_out, T);
}